// Round 1
// baseline (460.959 us; speedup 1.0000x reference)
//
#include <hip/hip_runtime.h>

#define N_NODES 50000
#define N_EDGES 1250000
#define EMBED 64
#define N_PAIRS (1024 * 100)

// ---------------- degree histogram ----------------
__global__ __launch_bounds__(256) void deg_kernel(const int* __restrict__ dst,
                                                  int* __restrict__ deg) {
    int i = blockIdx.x * 256 + threadIdx.x;
    if (i < N_EDGES) atomicAdd(&deg[dst[i]], 1);
}

// ---------------- single-block exclusive scan (two-level: wave shfl + LDS) ----------------
__global__ __launch_bounds__(1024) void scan_kernel(const int* __restrict__ deg,
                                                    int* __restrict__ row,
                                                    int* __restrict__ cursor) {
    __shared__ int wsum[16];
    __shared__ int carry_s;
    int t = threadIdx.x;
    int lane = t & 63, wid = t >> 6;
    if (t == 0) carry_s = 0;
    __syncthreads();
    for (int base = 0; base < N_NODES; base += 1024) {
        int i = base + t;
        int v = (i < N_NODES) ? deg[i] : 0;
        int incl = v;
        #pragma unroll
        for (int off = 1; off < 64; off <<= 1) {
            int o = __shfl_up(incl, off);
            if (lane >= off) incl += o;
        }
        if (lane == 63) wsum[wid] = incl;
        __syncthreads();
        if (t < 16) {
            int x = wsum[t];
            #pragma unroll
            for (int off = 1; off < 16; off <<= 1) {
                int o = __shfl_up(x, off);
                if (t >= off) x += o;
            }
            wsum[t] = x;  // inclusive prefix over wave sums
        }
        __syncthreads();
        int waveBase = (wid > 0) ? wsum[wid - 1] : 0;
        int excl = waveBase + incl - v;
        int carry = carry_s;
        if (i < N_NODES) {
            row[i] = carry + excl;
            cursor[i] = carry + excl;
        }
        int total = wsum[15];
        __syncthreads();              // all reads of carry_s / wsum done
        if (t == 0) carry_s = carry + total;
        __syncthreads();              // update visible before next tile
    }
    if (t == 0) row[N_NODES] = carry_s;
}

// ---------------- CSR fill (atomic cursor per dst) ----------------
__global__ __launch_bounds__(256) void fill_kernel(const int* __restrict__ src,
                                                   const int* __restrict__ dst,
                                                   int* __restrict__ cursor,
                                                   int* __restrict__ col) {
    int i = blockIdx.x * 256 + threadIdx.x;
    if (i < N_EDGES) {
        int d = dst[i];
        int pos = atomicAdd(&cursor[d], 1);
        col[pos] = src[i];
    }
}

// ---------------- fused mean-aggregate + linear + tanh; one wave per node ----------------
__global__ __launch_bounds__(256) void layer_kernel(const float* __restrict__ hin,
                                                    float* __restrict__ hout,
                                                    const float* __restrict__ W,
                                                    const float* __restrict__ bvec,
                                                    const int* __restrict__ row,
                                                    const int* __restrict__ col) {
    __shared__ float Wl[64][65];   // pitch 65 -> bank-conflict-free column reads
    __shared__ float aggL[4][64];
    int t = threadIdx.x;
    int wid = t >> 6, lane = t & 63;
    for (int i = t; i < 64 * 64; i += 256)
        Wl[i >> 6][i & 63] = W[i];

    int node = blockIdx.x * 4 + wid;   // grid is exactly N_NODES/4 blocks
    int start = row[node];
    int end = row[node + 1];
    float acc = 0.f;
    for (int base = start; base < end; base += 64) {
        int cnt = min(64, end - base);
        int sid = (lane < cnt) ? col[base + lane] : 0;
        for (int j = 0; j < cnt; ++j) {
            int s = __builtin_amdgcn_readlane(sid, j);   // scalar broadcast -> saddr+voffset load
            acc += hin[(size_t)s * EMBED + lane];
        }
    }
    int degn = end - start;
    float agg = (degn > 0) ? acc / (float)degn : 0.f;
    aggL[wid][lane] = agg;
    __syncthreads();   // covers Wl staging + aggL visibility

    float x = bvec[lane];   // lane = output feature j
    #pragma unroll
    for (int d = 0; d < 64; ++d)
        x += aggL[wid][d] * Wl[lane][d];
    hout[(size_t)node * EMBED + lane] = tanhf(x);
}

// ---------------- pair scoring: one wave per (b,k) pair ----------------
__global__ __launch_bounds__(256) void score_kernel(const float* __restrict__ h,
                                                    const int* __restrict__ ui,
                                                    const int* __restrict__ ii,
                                                    float* __restrict__ out) {
    int pair = blockIdx.x * 4 + (threadIdx.x >> 6);   // grid exactly N_PAIRS/4
    int lane = threadIdx.x & 63;
    int u = ui[pair];
    int v = ii[pair];
    float p = h[(size_t)u * EMBED + lane] * h[(size_t)v * EMBED + lane];
    #pragma unroll
    for (int off = 32; off > 0; off >>= 1)
        p += __shfl_down(p, off);
    if (lane == 0) out[pair] = p;
}

extern "C" void kernel_launch(void* const* d_in, const int* in_sizes, int n_in,
                              void* d_out, int out_size, void* d_ws, size_t ws_size,
                              hipStream_t stream) {
    const float* emb = (const float*)d_in[0];
    const float* W0  = (const float*)d_in[1];
    const float* b0  = (const float*)d_in[2];
    const float* W1  = (const float*)d_in[3];
    const float* b1  = (const float*)d_in[4];
    const int* src   = (const int*)d_in[5];
    const int* dst   = (const int*)d_in[6];
    const int* ui    = (const int*)d_in[7];
    const int* ii    = (const int*)d_in[8];
    float* out = (float*)d_out;

    char* p = (char*)d_ws;
    auto alloc = [&](size_t bytes) {
        char* r = p;
        p += (bytes + 255) & ~(size_t)255;
        return r;
    };
    int* deg    = (int*)alloc(sizeof(int) * N_NODES);
    int* row    = (int*)alloc(sizeof(int) * (N_NODES + 1));
    int* cursor = (int*)alloc(sizeof(int) * N_NODES);
    int* col    = (int*)alloc(sizeof(int) * N_EDGES);
    float* h1   = (float*)alloc(sizeof(float) * N_NODES * EMBED);
    float* h2   = (float*)alloc(sizeof(float) * N_NODES * EMBED);

    hipMemsetAsync(deg, 0, sizeof(int) * N_NODES, stream);
    deg_kernel<<<(N_EDGES + 255) / 256, 256, 0, stream>>>(dst, deg);
    scan_kernel<<<1, 1024, 0, stream>>>(deg, row, cursor);
    fill_kernel<<<(N_EDGES + 255) / 256, 256, 0, stream>>>(src, dst, cursor, col);
    layer_kernel<<<N_NODES / 4, 256, 0, stream>>>(emb, h1, W0, b0, row, col);
    layer_kernel<<<N_NODES / 4, 256, 0, stream>>>(h1, h2, W1, b1, row, col);
    score_kernel<<<N_PAIRS / 4, 256, 0, stream>>>(h2, ui, ii, out);
}

// Round 2
// 376.751 us; speedup vs baseline: 1.2235x; 1.2235x over previous
//
#include <hip/hip_runtime.h>

#define N_NODES 50000
#define N_EDGES 1250000
#define EMBED 64
#define N_PAIRS (1024 * 100)
#define NBLK 49   // ceil(50000/1024) scan blocks

// ---------------- degree histogram (int4 edges) ----------------
__global__ __launch_bounds__(256) void deg_kernel(const int* __restrict__ dst,
                                                  int* __restrict__ deg) {
    int idx4 = blockIdx.x * 256 + threadIdx.x;
    if (idx4 < N_EDGES / 4) {
        int4 d = ((const int4*)dst)[idx4];
        atomicAdd(&deg[d.x], 1);
        atomicAdd(&deg[d.y], 1);
        atomicAdd(&deg[d.z], 1);
        atomicAdd(&deg[d.w], 1);
    }
}

// ---------------- scan pass 1: per-block (1024 elems) sums ----------------
__global__ __launch_bounds__(256) void blocksum_kernel(const int* __restrict__ deg,
                                                       int* __restrict__ bsum) {
    int t = threadIdx.x;
    int idx4 = blockIdx.x * 256 + t;
    int4 v = {0, 0, 0, 0};
    if (idx4 < N_NODES / 4) v = ((const int4*)deg)[idx4];
    int s = v.x + v.y + v.z + v.w;
    #pragma unroll
    for (int off = 32; off > 0; off >>= 1) s += __shfl_down(s, off);
    __shared__ int ws[4];
    int lane = t & 63, wid = t >> 6;
    if (lane == 0) ws[wid] = s;
    __syncthreads();
    if (t == 0) bsum[blockIdx.x] = ws[0] + ws[1] + ws[2] + ws[3];
}

// ---------------- scan pass 2: scan the 49 block sums (1 wave) ----------------
__global__ __launch_bounds__(64) void bscan_kernel(const int* __restrict__ bsum,
                                                   int* __restrict__ boff,
                                                   int* __restrict__ rowend) {
    int t = threadIdx.x;
    int v = (t < NBLK) ? bsum[t] : 0;
    int incl = v;
    #pragma unroll
    for (int off = 1; off < 64; off <<= 1) {
        int o = __shfl_up(incl, off);
        if (t >= off) incl += o;
    }
    if (t < NBLK) boff[t] = incl - v;
    if (t == NBLK - 1) rowend[0] = incl;   // total edge count -> row[N_NODES]
}

// ---------------- scan pass 3: local scan + block offset -> row/cursor ----------------
__global__ __launch_bounds__(256) void scan2_kernel(const int* __restrict__ deg,
                                                    const int* __restrict__ boff,
                                                    int* __restrict__ row,
                                                    int* __restrict__ cursor) {
    int t = threadIdx.x;
    int idx4 = blockIdx.x * 256 + t;
    bool ok = idx4 < N_NODES / 4;
    int4 v = {0, 0, 0, 0};
    if (ok) v = ((const int4*)deg)[idx4];
    int s = v.x + v.y + v.z + v.w;
    int lane = t & 63, wid = t >> 6;
    int incl = s;
    #pragma unroll
    for (int off = 1; off < 64; off <<= 1) {
        int o = __shfl_up(incl, off);
        if (lane >= off) incl += o;
    }
    __shared__ int ws[4];
    if (lane == 63) ws[wid] = incl;
    __syncthreads();
    int wbase = 0;
    for (int w = 0; w < wid; ++w) wbase += ws[w];
    int ex = wbase + (incl - s) + boff[blockIdx.x];
    if (ok) {
        int4 r;
        r.x = ex;
        r.y = ex + v.x;
        r.z = ex + v.x + v.y;
        r.w = ex + v.x + v.y + v.z;
        ((int4*)row)[idx4] = r;
        ((int4*)cursor)[idx4] = r;
    }
}

// ---------------- CSR fill (atomic cursor per dst, int4 edge loads) ----------------
__global__ __launch_bounds__(256) void fill_kernel(const int* __restrict__ src,
                                                   const int* __restrict__ dst,
                                                   int* __restrict__ cursor,
                                                   int* __restrict__ col) {
    int idx4 = blockIdx.x * 256 + threadIdx.x;
    if (idx4 < N_EDGES / 4) {
        int4 s4 = ((const int4*)src)[idx4];
        int4 d4 = ((const int4*)dst)[idx4];
        int p0 = atomicAdd(&cursor[d4.x], 1); col[p0] = s4.x;
        int p1 = atomicAdd(&cursor[d4.y], 1); col[p1] = s4.y;
        int p2 = atomicAdd(&cursor[d4.z], 1); col[p2] = s4.z;
        int p3 = atomicAdd(&cursor[d4.w], 1); col[p3] = s4.w;
    }
}

// ---- fused mean-aggregate + linear + tanh; wave per node, 4 edges x float4 ----
__global__ __launch_bounds__(256) void layer_kernel(const float* __restrict__ hin,
                                                    float* __restrict__ hout,
                                                    const float* __restrict__ W,
                                                    const float* __restrict__ bvec,
                                                    const int* __restrict__ row,
                                                    const int* __restrict__ col) {
    __shared__ float Wl[64][65];   // pitch 65 -> conflict-free column reads
    __shared__ float aggL[4][64];
    int t = threadIdx.x;
    int wid = t >> 6, lane = t & 63;
    for (int i = t; i < 64 * 64; i += 256)
        Wl[i >> 6][i & 63] = W[i];

    int node = blockIdx.x * 4 + wid;   // grid exactly N_NODES/4
    int start = row[node];
    int end = row[node + 1];
    int g = lane >> 4;     // edge slot within chunk (0..3)
    int d16 = lane & 15;   // float4 slot (dims 4*d16 .. 4*d16+3)
    float4 acc = {0.f, 0.f, 0.f, 0.f};
    for (int base = start; base < end; base += 4) {
        int e = base + g;
        if (e < end) {
            int s = col[e];
            float4 v = ((const float4*)(hin + (size_t)s * EMBED))[d16];
            acc.x += v.x; acc.y += v.y; acc.z += v.z; acc.w += v.w;
        }
    }
    // sum across the 4 edge groups (xor 16, 32)
    #pragma unroll
    for (int off = 16; off < 64; off <<= 1) {
        acc.x += __shfl_xor(acc.x, off);
        acc.y += __shfl_xor(acc.y, off);
        acc.z += __shfl_xor(acc.z, off);
        acc.w += __shfl_xor(acc.w, off);
    }
    int degn = end - start;
    float inv = (degn > 0) ? 1.0f / (float)degn : 0.f;
    if (g == 0) {
        float4 a;
        a.x = acc.x * inv; a.y = acc.y * inv; a.z = acc.z * inv; a.w = acc.w * inv;
        ((float4*)aggL[wid])[d16] = a;
    }
    __syncthreads();   // covers Wl staging + aggL visibility

    float x = bvec[lane];   // lane = output feature j
    #pragma unroll
    for (int d = 0; d < 64; ++d)
        x += aggL[wid][d] * Wl[lane][d];
    hout[(size_t)node * EMBED + lane] = tanhf(x);
}

// ---------------- pair scoring: 16 lanes x float4 per pair ----------------
__global__ __launch_bounds__(256) void score_kernel(const float* __restrict__ h,
                                                    const int* __restrict__ ui,
                                                    const int* __restrict__ ii,
                                                    float* __restrict__ out) {
    int t = threadIdx.x;
    int idx = blockIdx.x * 16 + (t >> 4);   // grid exactly N_PAIRS/16
    int d16 = t & 15;
    int u = ui[idx];
    int v = ii[idx];
    float4 a = ((const float4*)(h + (size_t)u * EMBED))[d16];
    float4 b = ((const float4*)(h + (size_t)v * EMBED))[d16];
    float p = a.x * b.x + a.y * b.y + a.z * b.z + a.w * b.w;
    #pragma unroll
    for (int off = 8; off > 0; off >>= 1)
        p += __shfl_xor(p, off);
    if (d16 == 0) out[idx] = p;
}

extern "C" void kernel_launch(void* const* d_in, const int* in_sizes, int n_in,
                              void* d_out, int out_size, void* d_ws, size_t ws_size,
                              hipStream_t stream) {
    const float* emb = (const float*)d_in[0];
    const float* W0  = (const float*)d_in[1];
    const float* b0  = (const float*)d_in[2];
    const float* W1  = (const float*)d_in[3];
    const float* b1  = (const float*)d_in[4];
    const int* src   = (const int*)d_in[5];
    const int* dst   = (const int*)d_in[6];
    const int* ui    = (const int*)d_in[7];
    const int* ii    = (const int*)d_in[8];
    float* out = (float*)d_out;

    char* p = (char*)d_ws;
    auto alloc = [&](size_t bytes) {
        char* r = p;
        p += (bytes + 255) & ~(size_t)255;
        return r;
    };
    int* deg    = (int*)alloc(sizeof(int) * N_NODES);
    int* row    = (int*)alloc(sizeof(int) * (N_NODES + 1));
    int* cursor = (int*)alloc(sizeof(int) * N_NODES);
    int* col    = (int*)alloc(sizeof(int) * N_EDGES);
    int* bsum   = (int*)alloc(sizeof(int) * NBLK);
    int* boff   = (int*)alloc(sizeof(int) * NBLK);
    float* h1   = (float*)alloc(sizeof(float) * N_NODES * EMBED);
    float* h2   = (float*)alloc(sizeof(float) * N_NODES * EMBED);

    hipMemsetAsync(deg, 0, sizeof(int) * N_NODES, stream);
    int edge_blocks = (N_EDGES / 4 + 255) / 256;
    deg_kernel<<<edge_blocks, 256, 0, stream>>>(dst, deg);
    blocksum_kernel<<<NBLK, 256, 0, stream>>>(deg, bsum);
    bscan_kernel<<<1, 64, 0, stream>>>(bsum, boff, row + N_NODES);
    scan2_kernel<<<NBLK, 256, 0, stream>>>(deg, boff, row, cursor);
    fill_kernel<<<edge_blocks, 256, 0, stream>>>(src, dst, cursor, col);
    layer_kernel<<<N_NODES / 4, 256, 0, stream>>>(emb, h1, W0, b0, row, col);
    layer_kernel<<<N_NODES / 4, 256, 0, stream>>>(h1, h2, W1, b1, row, col);
    score_kernel<<<N_PAIRS / 16, 256, 0, stream>>>(h2, ui, ii, out);
}